// Round 8
// baseline (21505.960 us; speedup 1.0000x reference)
//
#include <hip/hip_runtime.h>
#include <cstdint>

#define BATCH 4
#define NPTS  32768
#define SKP   512
#define M1    (SKP*4)   /* 2048 */
#define KA    32
#define KB    2
#define SPHN  128

// FPS distance: reference _fps uses sum((x-c)**2) = ((dx*dx+dy*dy)+dz*dz),
// pinned round-to-nearest, NO fma contraction (bitwise == numpy).
__device__ __forceinline__ float sqdist(float px, float py, float pz,
                                        float cx, float cy, float cz) {
  float dx = px - cx, dy = py - cy, dz = pz - cz;
  return __fadd_rn(__fadd_rn(__fmul_rn(dx, dx), __fmul_rn(dy, dy)),
                   __fmul_rn(dz, dz));
}
// sklnz distance: reference _pairwise_sqdist uses c2 + p2 - 2*cp (Gram form):
// d2 = (q2 + p2) - 2*cp, cp = ((qx*px + qy*py) + qz*pz). Pinned, no fma.
__device__ __forceinline__ float d2gram(float px, float py, float pz,
                                        float qx, float qy, float qz, float q2) {
  float p2 = __fadd_rn(__fadd_rn(__fmul_rn(px, px), __fmul_rn(py, py)),
                       __fmul_rn(pz, pz));
  float cp = __fadd_rn(__fadd_rn(__fmul_rn(qx, px), __fmul_rn(qy, py)),
                       __fmul_rn(qz, pz));
  return __fsub_rn(__fadd_rn(q2, p2), __fadd_rn(cp, cp));
}

// ---------------------------------------------------------------------------
// Stage-1 FPS: one 1024-thread block per batch. x,y in VGPRs (64), z in LDS
// (128KB), dist[] in 32 VGPRs.
// amdgpu_waves_per_eu(4,4): pin occupancy to exactly 4 waves/EU (= the one
// 1024-thread block) so the allocator uses the full 128-VGPR budget instead
// of targeting 8 waves/EU at 64 VGPRs and spilling 64 floats/thread to
// scratch (R6/R7 profile: VGPR=64, 4.2 GB FETCH/dispatch, 18-49 ms).
// One barrier/iter. Tie-break: smaller index (jnp.argmax).
// ---------------------------------------------------------------------------
__global__ __launch_bounds__(1024)
__attribute__((amdgpu_waves_per_eu(4, 4)))
void fps1_kernel(const float* __restrict__ xyz, int* __restrict__ ids)
{
  int b = blockIdx.x;
  const float* X = xyz + (size_t)b * NPTS * 3;
  ids += (size_t)b * M1;
  int tid = threadIdx.x, lane = tid & 63, wave = tid >> 6;

  __shared__ float zsh[NPTS];          // 131072 B
  __shared__ float s_v[2][16];
  __shared__ int   s_i[2][16];

  float xr[32], yr[32], dist[32];
#pragma unroll
  for (int j = 0; j < 32; ++j) {
    int p = tid + 1024 * j;
    xr[j] = X[3*p];
    yr[j] = X[3*p+1];
    zsh[p] = X[3*p+2];
    dist[j] = 1e10f;
  }
  __syncthreads();

  if (tid == 0) ids[0] = 0;
  float cx = X[0], cy = X[1], cz = X[2];

  for (int it = 1; it < M1; ++it) {
    float best = -1.f; int besti = 0;
#pragma unroll
    for (int j = 0; j < 32; ++j) {
      int p = tid + 1024 * j;
      float d = sqdist(xr[j], yr[j], zsh[p], cx, cy, cz);
      d = fminf(dist[j], d);
      dist[j] = d;
      bool gt = d > best;
      best  = gt ? d : best;
      besti = gt ? p : besti;
    }
#pragma unroll
    for (int off = 32; off > 0; off >>= 1) {
      float ov = __shfl_xor(best, off);
      int   oi = __shfl_xor(besti, off);
      if (ov > best || (ov == best && oi < besti)) { best = ov; besti = oi; }
    }
    int par = it & 1;
    if (lane == 0) { s_v[par][wave] = best; s_i[par][wave] = besti; }
    __syncthreads();
    float v = -1.f; int i = 0x7fffffff;
    if (lane < 16) { v = s_v[par][lane]; i = s_i[par][lane]; }
#pragma unroll
    for (int off = 8; off > 0; off >>= 1) {
      float ov = __shfl_xor(v, off);
      int   oi = __shfl_xor(i, off);
      if (ov > v || (ov == v && oi < i)) { v = ov; i = oi; }
    }
    i = __shfl(i, 0);
    if (tid == 0) ids[it] = i;
    cx = X[3*i]; cy = X[3*i+1]; cz = X[3*i+2];
  }
}

// ---------------------------------------------------------------------------
// Stage-2 FPS on the 2048-pt intermediate skeleton (float4, L1-resident).
// ---------------------------------------------------------------------------
__global__ __launch_bounds__(256)
void fps2_kernel(const float4* __restrict__ pts, int* __restrict__ ids)
{
  const int PTS = 8, BLOCK = 256, NW = 4;
  int b = blockIdx.x;
  pts += (size_t)b * M1;
  ids += (size_t)b * SKP;
  int tid = threadIdx.x, lane = tid & 63, wave = tid >> 6;

  float dist[PTS];
#pragma unroll
  for (int j = 0; j < PTS; ++j) dist[j] = 1e10f;

  __shared__ float s_v[2][NW];
  __shared__ int   s_i[2][NW];
  if (tid == 0) ids[0] = 0;
  float4 piv = pts[0];
  float cx = piv.x, cy = piv.y, cz = piv.z;

  for (int it = 1; it < SKP; ++it) {
    float best = -1.f; int besti = 0;
#pragma unroll
    for (int j = 0; j < PTS; ++j) {
      int p = tid + BLOCK * j;
      float4 f = pts[p];
      float d = sqdist(f.x, f.y, f.z, cx, cy, cz);
      d = fminf(dist[j], d);
      dist[j] = d;
      bool gt = d > best;
      best  = gt ? d : best;
      besti = gt ? p : besti;
    }
#pragma unroll
    for (int off = 32; off > 0; off >>= 1) {
      float ov = __shfl_xor(best, off);
      int   oi = __shfl_xor(besti, off);
      if (ov > best || (ov == best && oi < besti)) { best = ov; besti = oi; }
    }
    int par = it & 1;
    if (lane == 0) { s_v[par][wave] = best; s_i[par][wave] = besti; }
    __syncthreads();
    float v = -1.f; int i = 0x7fffffff;
    if (lane < NW) { v = s_v[par][lane]; i = s_i[par][lane]; }
#pragma unroll
    for (int off = NW >> 1; off > 0; off >>= 1) {
      float ov = __shfl_xor(v, off);
      int   oi = __shfl_xor(i, off);
      if (ov > v || (ov == v && oi < i)) { v = ov; i = oi; }
    }
    i = __shfl(i, 0);
    if (tid == 0) ids[it] = i;
    float4 pv = pts[i];
    cx = pv.x; cy = pv.y; cz = pv.z;
  }
}

// ---------------------------------------------------------------------------
// Skeletonization: wave per query. Distances via the reference's GRAM form.
// Branch-free sorted top-K per lane (wave-uniform __any guard skips the
// insertion network when no lane would modify its list -- exact semantics),
// LDS heads-merge -> exact K-th smallest t (with multiplicity), then exact-K
// selection: accumulate d < t strictly, fill need = K - count(d<t) slots
// with d == t in ascending index order (lax.top_k tie semantics).
// S3=true: pts is f32 xyz triplets (stride 3); else float4.
// ---------------------------------------------------------------------------
template<int K, int N, bool S3>
__global__ __launch_bounds__(256)
void sklnz_kernel(const float4* __restrict__ queries,
                  const void*   __restrict__ ptsv,
                  float4* __restrict__ outc,
                  float*  __restrict__ outr,
                  int M)
{
  const int CH = N / 64;
  int wave = threadIdx.x >> 6, lane = threadIdx.x & 63;
  int qid = blockIdx.x * 4 + wave;
  int b = qid / M;
  const float*  P3 = (const float*)ptsv + (size_t)b * N * 3;
  const float4* P4 = (const float4*)ptsv + (size_t)b * N;
  float4 q = queries[qid];
  float q2 = __fadd_rn(__fadd_rn(__fmul_rn(q.x, q.x), __fmul_rn(q.y, q.y)),
                       __fmul_rn(q.z, q.z));

  float a[K];
#pragma unroll
  for (int s = 0; s < K; ++s) a[s] = 3.0e38f;

  for (int j = 0; j < CH; ++j) {
    int p = lane + 64 * j;
    float px, py, pz;
    if (S3) { px = P3[3*p]; py = P3[3*p+1]; pz = P3[3*p+2]; }
    else    { float4 f = P4[p]; px = f.x; py = f.y; pz = f.z; }
    float d = d2gram(px, py, pz, q.x, q.y, q.z, q2);
    if (__any(d < a[K-1])) {
#pragma unroll
      for (int s = K - 1; s > 0; --s) a[s] = fminf(a[s], fmaxf(a[s-1], d));
      a[0] = fminf(a[0], d);
    }
  }

  // merge 64 sorted lists -> t = K-th smallest of the union (with multiplicity)
  __shared__ float heads[4][64][K + 1];
#pragma unroll
  for (int s = 0; s < K; ++s) heads[wave][lane][s] = a[s];
  heads[wave][lane][K] = 3.1e38f;
  int h = 0; float t = 0.f;
  for (int r = 0; r < K; ++r) {
    float mv = heads[wave][lane][h];
    int   ml = lane;
#pragma unroll
    for (int off = 32; off > 0; off >>= 1) {
      float ov = __shfl_xor(mv, off);
      int   ol = __shfl_xor(ml, off);
      if (ov < mv || (ov == mv && ol < ml)) { mv = ov; ml = ol; }
    }
    t = mv;
    if (ml == lane) h++;
  }

  // rescan: accumulate strictly d < t; remember per-lane first d == t index
  float sx = 0.f, sy = 0.f, sz = 0.f, sr = 0.f;
  int cl = 0;
  int myNext = 0x7fffffff;
  for (int j = 0; j < CH; ++j) {
    int p = lane + 64 * j;
    float px, py, pz;
    if (S3) { px = P3[3*p]; py = P3[3*p+1]; pz = P3[3*p+2]; }
    else    { float4 f = P4[p]; px = f.x; py = f.y; pz = f.z; }
    float d = d2gram(px, py, pz, q.x, q.y, q.z, q2);
    if (d < t) { sx += px; sy += py; sz += pz; sr += sqrtf(fmaxf(d, 0.f)); cl++; }
    else if (d == t && myNext == 0x7fffffff) myNext = p;  // scan order => smallest p
  }
  int ctot = cl;
#pragma unroll
  for (int off = 32; off > 0; off >>= 1) ctot += __shfl_xor(ctot, off);
  int need = K - ctot;   // >= 1 (t itself), <= multiplicity of t
  float rt = sqrtf(fmaxf(t, 0.f));

  for (int e = 0; e < need; ++e) {
    int mn = myNext;
#pragma unroll
    for (int off = 32; off > 0; off >>= 1) mn = min(mn, __shfl_xor(mn, off));
    if (myNext == mn) {           // unique owner (index sets disjoint mod 64)
      float px, py, pz;
      if (S3) { px = P3[3*mn]; py = P3[3*mn+1]; pz = P3[3*mn+2]; }
      else    { float4 f = P4[mn]; px = f.x; py = f.y; pz = f.z; }
      sx += px; sy += py; sz += pz; sr += rt;
      int nx = 0x7fffffff;
      for (int j = (mn - lane) / 64 + 1; j < CH; ++j) {
        int p = lane + 64 * j;
        float ux, uy, uz;
        if (S3) { ux = P3[3*p]; uy = P3[3*p+1]; uz = P3[3*p+2]; }
        else    { float4 f = P4[p]; ux = f.x; uy = f.y; uz = f.z; }
        float d = d2gram(ux, uy, uz, q.x, q.y, q.z, q2);
        if (d == t) { nx = p; break; }
      }
      myNext = nx;
    }
  }

#pragma unroll
  for (int off = 32; off > 0; off >>= 1) {
    sx += __shfl_xor(sx, off);
    sy += __shfl_xor(sy, off);
    sz += __shfl_xor(sz, off);
    sr += __shfl_xor(sr, off);
  }
  if (lane == 0) {
    const float inv = 1.0f / (float)K;
    outc[qid] = make_float4(sx * inv, sy * inv, sz * inv, 0.f);
    outr[qid] = sr * inv;
  }
}

// ---------------------------------------------------------------------------
__global__ void gather1_kernel(const float* __restrict__ xyz,
                               const int* __restrict__ ids,
                               float4* __restrict__ cen)
{
  int g = blockIdx.x * 256 + threadIdx.x;
  if (g >= BATCH * M1) return;
  int b = g / M1;
  size_t base = ((size_t)b * NPTS + ids[g]) * 3;
  cen[g] = make_float4(xyz[base], xyz[base+1], xyz[base+2], 0.f);
}

__global__ void gather2_kernel(const float4* __restrict__ cen4,
                               const float* __restrict__ rad1,
                               const int* __restrict__ ids2,
                               float4* __restrict__ cen2,
                               float* __restrict__ radg)
{
  int g = blockIdx.x * 256 + threadIdx.x;
  if (g >= BATCH * SKP) return;
  int b = g / SKP;
  int p = ids2[g];
  cen2[g] = cen4[(size_t)b * M1 + p];
  radg[g] = rad1[(size_t)b * M1 + p];
}

__global__ void finalize_kernel(const float4* __restrict__ cen,
                                const float* __restrict__ radg,
                                const float* __restrict__ rad2,
                                const float* __restrict__ tmpl,
                                float* __restrict__ out)
{
  int g = blockIdx.x * 256 + threadIdx.x;   // one thread per sphere point
  int s = g >> 7;                            // sphere id 0..BATCH*SKP-1
  int j = g & 127;                           // template point id
  float4 c = cen[s];
  float r = __fmul_rn(__fadd_rn(radg[s], rad2[s]), 1.5f);
  float tx = tmpl[3*j], ty = tmpl[3*j+1], tz = tmpl[3*j+2];
  float* sp = out + BATCH * SKP * 3;
  sp[3*g]     = __fadd_rn(c.x, __fmul_rn(r, tx));
  sp[3*g + 1] = __fadd_rn(c.y, __fmul_rn(r, ty));
  sp[3*g + 2] = __fadd_rn(c.z, __fmul_rn(r, tz));
  if (j == 0) {
    out[3*s] = c.x; out[3*s+1] = c.y; out[3*s+2] = c.z;
    out[BATCH*SKP*3 + BATCH*SKP*SPHN*3 + s] = r;
  }
}

// ---------------------------------------------------------------------------
extern "C" void kernel_launch(void* const* d_in, const int* in_sizes, int n_in,
                              void* d_out, int out_size, void* d_ws, size_t ws_size,
                              hipStream_t stream)
{
  const float* xyz  = (const float*)d_in[0];   // f32 [B, N, 3]
  const float* tmpl = (const float*)d_in[1];   // f32 [128, 3]
  float* out = (float*)d_out;                  // f32 outputs
  char* ws = (char*)d_ws;

  // total ws footprint: 417,792 B
  int*    ids1  = (int*)   (ws + 0);        //  32768 B
  float4* cen4a = (float4*)(ws + 32768);    // 131072 B
  float4* cen4b = (float4*)(ws + 163840);   // 131072 B
  float*  rad1  = (float*) (ws + 294912);   //  32768 B
  int*    ids2  = (int*)   (ws + 327680);   //   8192 B
  float4* cen2a = (float4*)(ws + 335872);   //  32768 B
  float4* cen2b = (float4*)(ws + 368640);   //  32768 B
  float*  radg  = (float*) (ws + 401408);   //   8192 B
  float*  rad2  = (float*) (ws + 409600);   //   8192 B

  // Stage 1: FPS to 2048 seeds per batch
  fps1_kernel<<<BATCH, 1024, 0, stream>>>(xyz, ids1);
  gather1_kernel<<<(BATCH * M1 + 255) / 256, 256, 0, stream>>>(xyz, ids1, cen4a);
  // two skeletonization passes, k=32, against the full f32 cloud
  sklnz_kernel<KA, NPTS, true><<<BATCH * M1 / 4, 256, 0, stream>>>(cen4a, xyz, cen4b, rad1, M1);
  sklnz_kernel<KA, NPTS, true><<<BATCH * M1 / 4, 256, 0, stream>>>(cen4b, xyz, cen4a, rad1, M1);
  // Stage 2: FPS 2048 -> 512 on intermediate skeleton (cen4a)
  fps2_kernel<<<BATCH, 256, 0, stream>>>(cen4a, ids2);
  gather2_kernel<<<(BATCH * SKP + 255) / 256, 256, 0, stream>>>(cen4a, rad1, ids2, cen2a, radg);
  // two skeletonization passes, k=2, against the 2048-point skeleton
  sklnz_kernel<KB, M1, false><<<BATCH * SKP / 4, 256, 0, stream>>>(cen2a, cen4a, cen2b, rad2, SKP);
  sklnz_kernel<KB, M1, false><<<BATCH * SKP / 4, 256, 0, stream>>>(cen2b, cen4a, cen2a, rad2, SKP);
  // Outputs: centers, sphere points, radii (f32)
  finalize_kernel<<<BATCH * SKP * SPHN / 256, 256, 0, stream>>>(cen2a, radg, rad2, tmpl, out);
}

// Round 9
// 19943.654 us; speedup vs baseline: 1.0783x; 1.0783x over previous
//
#include <hip/hip_runtime.h>
#include <cstdint>

#define BATCH 4
#define NPTS  32768
#define SKP   512
#define M1    (SKP*4)   /* 2048 */
#define KA    32
#define KB    2
#define SPHN  128

// FPS distance: reference _fps uses sum((x-c)**2) = ((dx*dx+dy*dy)+dz*dz),
// pinned round-to-nearest, NO fma contraction (bitwise == numpy).
__device__ __forceinline__ float sqdist(float px, float py, float pz,
                                        float cx, float cy, float cz) {
  float dx = px - cx, dy = py - cy, dz = pz - cz;
  return __fadd_rn(__fadd_rn(__fmul_rn(dx, dx), __fmul_rn(dy, dy)),
                   __fmul_rn(dz, dz));
}
// sklnz distance: reference _pairwise_sqdist uses c2 + p2 - 2*cp (Gram form):
// d2 = (q2 + p2) - 2*cp, cp = ((qx*px + qy*py) + qz*pz). Pinned, no fma.
__device__ __forceinline__ float d2gram(float px, float py, float pz,
                                        float qx, float qy, float qz, float q2) {
  float p2 = __fadd_rn(__fadd_rn(__fmul_rn(px, px), __fmul_rn(py, py)),
                       __fmul_rn(pz, pz));
  float cp = __fadd_rn(__fadd_rn(__fmul_rn(qx, px), __fmul_rn(qy, py)),
                       __fmul_rn(qz, pz));
  return __fsub_rn(__fadd_rn(q2, p2), __fadd_rn(cp, cp));
}

// ---------------------------------------------------------------------------
// SoA prep: xyz [B][N][3] -> xy2 [B*N] float2 (lives in d_out scratch space;
// finalize_kernel fully overwrites d_out at the end of the pipeline).
// ---------------------------------------------------------------------------
__global__ void soa_kernel(const float* __restrict__ xyz,
                           float2* __restrict__ xy2)
{
  int p = blockIdx.x * 256 + threadIdx.x;
  if (p >= BATCH * NPTS) return;
  xy2[p] = make_float2(xyz[3*p], xyz[3*p+1]);
}

// ---------------------------------------------------------------------------
// Stage-1 FPS: one 1024-thread block per batch. Register budget kept <= 64
// VGPRs deliberately (R6-R8: allocator pins 64 VGPRs for 1024-thr blocks and
// spilled the old 96-float working set -> 9us/iter scratch-latency chains).
// New layout: dist[32] in VGPRs, z in LDS (128KB), x/y STREAMED per
// iteration from the SoA float2 array (coalesced, L2-resident, 262KB/iter)
// with an 8-deep manual prefetch ring. One barrier/iter; tie-break: smaller
// index (jnp.argmax).
// ---------------------------------------------------------------------------
__global__ __launch_bounds__(1024)
void fps1_kernel(const float* __restrict__ xyz,
                 const float2* __restrict__ xy2,
                 int* __restrict__ ids)
{
  int b = blockIdx.x;
  const float* X = xyz + (size_t)b * NPTS * 3;
  const float2* XY = xy2 + (size_t)b * NPTS;
  ids += (size_t)b * M1;
  int tid = threadIdx.x, lane = tid & 63, wave = tid >> 6;

  __shared__ float zsh[NPTS];          // 131072 B
  __shared__ float s_v[2][16];
  __shared__ int   s_i[2][16];

  float dist[32];
#pragma unroll
  for (int j = 0; j < 32; ++j) {
    int p = tid + 1024 * j;
    zsh[p] = X[3*p+2];
    dist[j] = 1e10f;
  }
  __syncthreads();

  if (tid == 0) ids[0] = 0;
  float2 c0 = XY[0];
  float cx = c0.x, cy = c0.y, cz = zsh[0];

  for (int it = 1; it < M1; ++it) {
    float best = -1.f; int besti = 0;
    float2 pf[8];
#pragma unroll
    for (int j0 = 0; j0 < 8; ++j0) pf[j0] = XY[tid + 1024 * j0];
#pragma unroll
    for (int j = 0; j < 32; ++j) {
      int p = tid + 1024 * j;
      float2 c2 = pf[j & 7];
      if (j + 8 < 32) pf[j & 7] = XY[tid + 1024 * (j + 8)];
      float d = sqdist(c2.x, c2.y, zsh[p], cx, cy, cz);
      d = fminf(dist[j], d);
      dist[j] = d;
      bool gt = d > best;
      best  = gt ? d : best;
      besti = gt ? p : besti;
    }
#pragma unroll
    for (int off = 32; off > 0; off >>= 1) {
      float ov = __shfl_xor(best, off);
      int   oi = __shfl_xor(besti, off);
      if (ov > best || (ov == best && oi < besti)) { best = ov; besti = oi; }
    }
    int par = it & 1;
    if (lane == 0) { s_v[par][wave] = best; s_i[par][wave] = besti; }
    __syncthreads();
    float v = -1.f; int i = 0x7fffffff;
    if (lane < 16) { v = s_v[par][lane]; i = s_i[par][lane]; }
#pragma unroll
    for (int off = 8; off > 0; off >>= 1) {
      float ov = __shfl_xor(v, off);
      int   oi = __shfl_xor(i, off);
      if (ov > v || (ov == v && oi < i)) { v = ov; i = oi; }
    }
    i = __shfl(i, 0);
    if (tid == 0) ids[it] = i;
    float2 pv = XY[i];
    cx = pv.x; cy = pv.y; cz = zsh[i];
  }
}

// ---------------------------------------------------------------------------
// Stage-2 FPS on the 2048-pt intermediate skeleton. Points staged once into
// LDS (32KB) -> per-iter reads are ds_read_b128 instead of global-latency
// chains.
// ---------------------------------------------------------------------------
__global__ __launch_bounds__(256)
void fps2_kernel(const float4* __restrict__ pts, int* __restrict__ ids)
{
  const int PTS = 8, BLOCK = 256, NW = 4;
  int b = blockIdx.x;
  pts += (size_t)b * M1;
  ids += (size_t)b * SKP;
  int tid = threadIdx.x, lane = tid & 63, wave = tid >> 6;

  __shared__ float4 pl[M1];            // 32768 B
  __shared__ float s_v[2][NW];
  __shared__ int   s_i[2][NW];

  float dist[PTS];
#pragma unroll
  for (int j = 0; j < PTS; ++j) {
    int p = tid + BLOCK * j;
    pl[p] = pts[p];
    dist[j] = 1e10f;
  }
  __syncthreads();

  if (tid == 0) ids[0] = 0;
  float4 piv = pl[0];
  float cx = piv.x, cy = piv.y, cz = piv.z;

  for (int it = 1; it < SKP; ++it) {
    float best = -1.f; int besti = 0;
#pragma unroll
    for (int j = 0; j < PTS; ++j) {
      int p = tid + BLOCK * j;
      float4 f = pl[p];
      float d = sqdist(f.x, f.y, f.z, cx, cy, cz);
      d = fminf(dist[j], d);
      dist[j] = d;
      bool gt = d > best;
      best  = gt ? d : best;
      besti = gt ? p : besti;
    }
#pragma unroll
    for (int off = 32; off > 0; off >>= 1) {
      float ov = __shfl_xor(best, off);
      int   oi = __shfl_xor(besti, off);
      if (ov > best || (ov == best && oi < besti)) { best = ov; besti = oi; }
    }
    int par = it & 1;
    if (lane == 0) { s_v[par][wave] = best; s_i[par][wave] = besti; }
    __syncthreads();
    float v = -1.f; int i = 0x7fffffff;
    if (lane < NW) { v = s_v[par][lane]; i = s_i[par][lane]; }
#pragma unroll
    for (int off = NW >> 1; off > 0; off >>= 1) {
      float ov = __shfl_xor(v, off);
      int   oi = __shfl_xor(i, off);
      if (ov > v || (ov == v && oi < i)) { v = ov; i = oi; }
    }
    i = __shfl(i, 0);
    if (tid == 0) ids[it] = i;
    float4 pv = pl[i];
    cx = pv.x; cy = pv.y; cz = pv.z;
  }
}

// ---------------------------------------------------------------------------
// Skeletonization: wave per query. Distances via the reference's GRAM form.
// Branch-free sorted top-K per lane, LDS heads-merge -> exact K-th smallest
// t (with multiplicity), then exact-K selection: accumulate d < t strictly,
// fill need = K - count(d<t) slots with d == t in ascending index order
// (lax.top_k tie semantics). S3=true: pts is f32 xyz triplets; else float4.
// ---------------------------------------------------------------------------
template<int K, int N, bool S3>
__global__ __launch_bounds__(256)
void sklnz_kernel(const float4* __restrict__ queries,
                  const void*   __restrict__ ptsv,
                  float4* __restrict__ outc,
                  float*  __restrict__ outr,
                  int M)
{
  const int CH = N / 64;
  int wave = threadIdx.x >> 6, lane = threadIdx.x & 63;
  int qid = blockIdx.x * 4 + wave;
  int b = qid / M;
  const float*  P3 = (const float*)ptsv + (size_t)b * N * 3;
  const float4* P4 = (const float4*)ptsv + (size_t)b * N;
  float4 q = queries[qid];
  float q2 = __fadd_rn(__fadd_rn(__fmul_rn(q.x, q.x), __fmul_rn(q.y, q.y)),
                       __fmul_rn(q.z, q.z));

  float a[K];
#pragma unroll
  for (int s = 0; s < K; ++s) a[s] = 3.0e38f;

  for (int j = 0; j < CH; ++j) {
    int p = lane + 64 * j;
    float px, py, pz;
    if (S3) { px = P3[3*p]; py = P3[3*p+1]; pz = P3[3*p+2]; }
    else    { float4 f = P4[p]; px = f.x; py = f.y; pz = f.z; }
    float d = d2gram(px, py, pz, q.x, q.y, q.z, q2);
#pragma unroll
    for (int s = K - 1; s > 0; --s) a[s] = fminf(a[s], fmaxf(a[s-1], d));
    a[0] = fminf(a[0], d);
  }

  // merge 64 sorted lists -> t = K-th smallest of the union (with multiplicity)
  __shared__ float heads[4][64][K + 1];
#pragma unroll
  for (int s = 0; s < K; ++s) heads[wave][lane][s] = a[s];
  heads[wave][lane][K] = 3.1e38f;
  int h = 0; float t = 0.f;
  for (int r = 0; r < K; ++r) {
    float mv = heads[wave][lane][h];
    int   ml = lane;
#pragma unroll
    for (int off = 32; off > 0; off >>= 1) {
      float ov = __shfl_xor(mv, off);
      int   ol = __shfl_xor(ml, off);
      if (ov < mv || (ov == mv && ol < ml)) { mv = ov; ml = ol; }
    }
    t = mv;
    if (ml == lane) h++;
  }

  // rescan: accumulate strictly d < t; remember per-lane first d == t index
  float sx = 0.f, sy = 0.f, sz = 0.f, sr = 0.f;
  int cl = 0;
  int myNext = 0x7fffffff;
  for (int j = 0; j < CH; ++j) {
    int p = lane + 64 * j;
    float px, py, pz;
    if (S3) { px = P3[3*p]; py = P3[3*p+1]; pz = P3[3*p+2]; }
    else    { float4 f = P4[p]; px = f.x; py = f.y; pz = f.z; }
    float d = d2gram(px, py, pz, q.x, q.y, q.z, q2);
    if (d < t) { sx += px; sy += py; sz += pz; sr += sqrtf(fmaxf(d, 0.f)); cl++; }
    else if (d == t && myNext == 0x7fffffff) myNext = p;  // scan order => smallest p
  }
  int ctot = cl;
#pragma unroll
  for (int off = 32; off > 0; off >>= 1) ctot += __shfl_xor(ctot, off);
  int need = K - ctot;   // >= 1 (t itself), <= multiplicity of t
  float rt = sqrtf(fmaxf(t, 0.f));

  for (int e = 0; e < need; ++e) {
    int mn = myNext;
#pragma unroll
    for (int off = 32; off > 0; off >>= 1) mn = min(mn, __shfl_xor(mn, off));
    if (myNext == mn) {           // unique owner (index sets disjoint mod 64)
      float px, py, pz;
      if (S3) { px = P3[3*mn]; py = P3[3*mn+1]; pz = P3[3*mn+2]; }
      else    { float4 f = P4[mn]; px = f.x; py = f.y; pz = f.z; }
      sx += px; sy += py; sz += pz; sr += rt;
      int nx = 0x7fffffff;
      for (int j = (mn - lane) / 64 + 1; j < CH; ++j) {
        int p = lane + 64 * j;
        float ux, uy, uz;
        if (S3) { ux = P3[3*p]; uy = P3[3*p+1]; uz = P3[3*p+2]; }
        else    { float4 f = P4[p]; ux = f.x; uy = f.y; uz = f.z; }
        float d = d2gram(ux, uy, uz, q.x, q.y, q.z, q2);
        if (d == t) { nx = p; break; }
      }
      myNext = nx;
    }
  }

#pragma unroll
  for (int off = 32; off > 0; off >>= 1) {
    sx += __shfl_xor(sx, off);
    sy += __shfl_xor(sy, off);
    sz += __shfl_xor(sz, off);
    sr += __shfl_xor(sr, off);
  }
  if (lane == 0) {
    const float inv = 1.0f / (float)K;
    outc[qid] = make_float4(sx * inv, sy * inv, sz * inv, 0.f);
    outr[qid] = sr * inv;
  }
}

// ---------------------------------------------------------------------------
__global__ void gather1_kernel(const float* __restrict__ xyz,
                               const int* __restrict__ ids,
                               float4* __restrict__ cen)
{
  int g = blockIdx.x * 256 + threadIdx.x;
  if (g >= BATCH * M1) return;
  int b = g / M1;
  size_t base = ((size_t)b * NPTS + ids[g]) * 3;
  cen[g] = make_float4(xyz[base], xyz[base+1], xyz[base+2], 0.f);
}

__global__ void gather2_kernel(const float4* __restrict__ cen4,
                               const float* __restrict__ rad1,
                               const int* __restrict__ ids2,
                               float4* __restrict__ cen2,
                               float* __restrict__ radg)
{
  int g = blockIdx.x * 256 + threadIdx.x;
  if (g >= BATCH * SKP) return;
  int b = g / SKP;
  int p = ids2[g];
  cen2[g] = cen4[(size_t)b * M1 + p];
  radg[g] = rad1[(size_t)b * M1 + p];
}

__global__ void finalize_kernel(const float4* __restrict__ cen,
                                const float* __restrict__ radg,
                                const float* __restrict__ rad2,
                                const float* __restrict__ tmpl,
                                float* __restrict__ out)
{
  int g = blockIdx.x * 256 + threadIdx.x;   // one thread per sphere point
  int s = g >> 7;                            // sphere id 0..BATCH*SKP-1
  int j = g & 127;                           // template point id
  float4 c = cen[s];
  float r = __fmul_rn(__fadd_rn(radg[s], rad2[s]), 1.5f);
  float tx = tmpl[3*j], ty = tmpl[3*j+1], tz = tmpl[3*j+2];
  float* sp = out + BATCH * SKP * 3;
  sp[3*g]     = __fadd_rn(c.x, __fmul_rn(r, tx));
  sp[3*g + 1] = __fadd_rn(c.y, __fmul_rn(r, ty));
  sp[3*g + 2] = __fadd_rn(c.z, __fmul_rn(r, tz));
  if (j == 0) {
    out[3*s] = c.x; out[3*s+1] = c.y; out[3*s+2] = c.z;
    out[BATCH*SKP*3 + BATCH*SKP*SPHN*3 + s] = r;
  }
}

// ---------------------------------------------------------------------------
extern "C" void kernel_launch(void* const* d_in, const int* in_sizes, int n_in,
                              void* d_out, int out_size, void* d_ws, size_t ws_size,
                              hipStream_t stream)
{
  const float* xyz  = (const float*)d_in[0];   // f32 [B, N, 3]
  const float* tmpl = (const float*)d_in[1];   // f32 [128, 3]
  float* out = (float*)d_out;                  // f32 outputs
  char* ws = (char*)d_ws;

  // total ws footprint: 417,792 B
  int*    ids1  = (int*)   (ws + 0);        //  32768 B
  float4* cen4a = (float4*)(ws + 32768);    // 131072 B
  float4* cen4b = (float4*)(ws + 163840);   // 131072 B
  float*  rad1  = (float*) (ws + 294912);   //  32768 B
  int*    ids2  = (int*)   (ws + 327680);   //   8192 B
  float4* cen2a = (float4*)(ws + 335872);   //  32768 B
  float4* cen2b = (float4*)(ws + 368640);   //  32768 B
  float*  radg  = (float*) (ws + 401408);   //   8192 B
  float*  rad2  = (float*) (ws + 409600);   //   8192 B

  // SoA xy staging lives in d_out (3.18 MB >= 1 MB needed); finalize_kernel
  // fully overwrites d_out at the end of every launch.
  float2* xy2 = (float2*)d_out;             // BATCH*NPTS float2 = 1 MB

  soa_kernel<<<(BATCH * NPTS + 255) / 256, 256, 0, stream>>>(xyz, xy2);
  // Stage 1: FPS to 2048 seeds per batch
  fps1_kernel<<<BATCH, 1024, 0, stream>>>(xyz, xy2, ids1);
  gather1_kernel<<<(BATCH * M1 + 255) / 256, 256, 0, stream>>>(xyz, ids1, cen4a);
  // two skeletonization passes, k=32, against the full f32 cloud
  sklnz_kernel<KA, NPTS, true><<<BATCH * M1 / 4, 256, 0, stream>>>(cen4a, xyz, cen4b, rad1, M1);
  sklnz_kernel<KA, NPTS, true><<<BATCH * M1 / 4, 256, 0, stream>>>(cen4b, xyz, cen4a, rad1, M1);
  // Stage 2: FPS 2048 -> 512 on intermediate skeleton (cen4a)
  fps2_kernel<<<BATCH, 256, 0, stream>>>(cen4a, ids2);
  gather2_kernel<<<(BATCH * SKP + 255) / 256, 256, 0, stream>>>(cen4a, rad1, ids2, cen2a, radg);
  // two skeletonization passes, k=2, against the 2048-point skeleton
  sklnz_kernel<KB, M1, false><<<BATCH * SKP / 4, 256, 0, stream>>>(cen2a, cen4a, cen2b, rad2, SKP);
  sklnz_kernel<KB, M1, false><<<BATCH * SKP / 4, 256, 0, stream>>>(cen2b, cen4a, cen2a, rad2, SKP);
  // Outputs: centers, sphere points, radii (f32)
  finalize_kernel<<<BATCH * SKP * SPHN / 256, 256, 0, stream>>>(cen2a, radg, rad2, tmpl, out);
}